// Round 12
// baseline (129.797 us; speedup 1.0000x reference)
//
#include <hip/hip_runtime.h>

// Round 12: barrier-free wave-streaming rewrite. Each wave owns a 128-col x
// 16-row band (2 cols/lane), streaming down rows with a rolling register
// pipeline: gray rows (s-1,s,s+1) -> sobel(s) -> rolling 3 mask rows ->
// OR-3x3 blur -> losses. Horizontal neighbors via __shfl, vertical via
// rolling regs, NO __syncthreads in the hot path (the champion's structural
// stall). Strip-boundary cols re-loaded by lanes 0/63 (reflect-equivalent,
// exactness proven by champion's halo scheme). Loads pipelined 2 rows ahead.
// Numerics identical to champion: u8 quantize, RNE int sobel, OR-blur == blur>0,
// Pk = D|Su<<10|St<<20 (f32-exact, ints <= 765).

constexpr int Bn = 16, Hn = 512, Wn = 512;
constexpr int BH = 16;                      // output rows per wave
constexpr int NSTRIP = 4;                   // 128-col strips
constexpr int NBAND = Hn / BH;              // 32
constexpr int NWAVE = NSTRIP * NBAND * Bn;  // 2048
constexpr int NBLK = NWAVE / 4;             // 512 blocks x 4 waves

__device__ __forceinline__ float u8q(float v) {
    return floorf(fminf(fmaxf(v * 255.0f, 0.0f), 255.0f));
}
__device__ __forceinline__ int reflect101(int i, int n) {
    if (i < 0) return -i;
    if (i >= n) return 2 * n - 2 - i;
    return i;
}
__device__ __forceinline__ int gray1(float r, float g, float b) {
    return (int)rintf((0.299f * r + 0.587f * g) + 0.114f * b);
}
__device__ __forceinline__ int iabs(int v) { return v < 0 ? -v : v; }
// packed gray: b0=pred c0, b1=true c0, b2=pred c1, b3=true c1
__device__ __forceinline__ unsigned packG(int gp0, int gt0, int gp1, int gt1) {
    return (unsigned)gp0 | ((unsigned)gt0 << 8) | ((unsigned)gp1 << 16) |
           ((unsigned)gt1 << 24);
}
__device__ __forceinline__ int sob1(int gl, int gr, int gu, int gd) {
    const int n = iabs(gr - gl) + iabs(gd - gu);
    const int h = n >> 1;
    return h + (n & h & 1);   // RNE(n/2)
}

__global__ __launch_bounds__(256, 2)
void csl_stream(const float* __restrict__ pred, const float* __restrict__ tru,
                int2* __restrict__ ws) {
    const int tid = threadIdx.x;
    const int lane = tid & 63;
    const int wid = blockIdx.x * 4 + (tid >> 6);
    const int strip = wid & (NSTRIP - 1);
    const int band = (wid >> 2) & (NBAND - 1);
    const int img = wid >> 7;
    const int bs = band * BH;
    const int x0w = strip * 128;
    const int x0 = x0w + 2 * lane;          // owned cols x0, x0+1

    const size_t chs = (size_t)Hn * Wn;
    const float* pb = pred + (size_t)img * 3 * chs;
    const float* tb = tru + (size_t)img * 3 * chs;

    // boundary cols (used by lanes 0 / 63 only)
    const bool isb = (lane == 0) || (lane == 63);
    const int bc0 = (lane == 0) ? reflect101(x0w - 2, Wn) : reflect101(x0w + 128, Wn);
    const int bc1 = (lane == 0) ? reflect101(x0w - 1, Wn) : reflect101(x0w + 129, Wn);

    float2 LA[6], LB[6];   // main load sets (pred RGB, true RGB), 2 rows in flight
    float bv[12];          // boundary dwords: [0..5]=slot0 ch, [6..11]=slot1 ch

    auto ldMain = [&](int gy, float2* L) {
        const int gyR = reflect101(gy, Hn);
        const float* p0 = pb + (size_t)gyR * Wn + x0;
        const float* t0 = tb + (size_t)gyR * Wn + x0;
        L[0] = *(const float2*)(p0);
        L[1] = *(const float2*)(p0 + chs);
        L[2] = *(const float2*)(p0 + 2 * chs);
        L[3] = *(const float2*)(t0);
        L[4] = *(const float2*)(t0 + chs);
        L[5] = *(const float2*)(t0 + 2 * chs);
    };
    auto ldBound = [&](int gy) {
        if (isb) {
            const size_t r0 = (size_t)reflect101(gy, Hn) * Wn;
            bv[0] = pb[r0 + bc0]; bv[1] = pb[r0 + bc0 + chs]; bv[2] = pb[r0 + bc0 + 2 * chs];
            bv[3] = tb[r0 + bc0]; bv[4] = tb[r0 + bc0 + chs]; bv[5] = tb[r0 + bc0 + 2 * chs];
            bv[6] = pb[r0 + bc1]; bv[7] = pb[r0 + bc1 + chs]; bv[8] = pb[r0 + bc1 + 2 * chs];
            bv[9] = tb[r0 + bc1]; bv[10] = tb[r0 + bc1 + chs]; bv[11] = tb[r0 + bc1 + 2 * chs];
        }
    };

    unsigned G1 = 0, G2 = 0;       // gray rows s-1, s (packed)
    unsigned Gx1 = 0, Gx2 = 0;     // boundary-col gray rolling (lanes 0/63)
    unsigned mk1 = 0, mk2 = 0;     // mask-code rows rolling (2b+2b+2b packed)
    int Pk1a = 0, Pk1b = 0, Pk2a = 0, Pk2b = 0;
    int accS = 0, accE = 0;

    ldMain(bs - 2, LA);
    ldMain(bs - 1, LB);
    ldBound(bs - 2);

    auto step = [&](int i, float2* L) {
        const int gy = bs - 2 + i;
        // ---- consume main row gy -> Gn, Pk ----
        const float pr0 = u8q(L[0].x), pg0 = u8q(L[1].x), pl0 = u8q(L[2].x);
        const float tr0 = u8q(L[3].x), tg0 = u8q(L[4].x), tl0 = u8q(L[5].x);
        const float pr1 = u8q(L[0].y), pg1 = u8q(L[1].y), pl1 = u8q(L[2].y);
        const float tr1 = u8q(L[3].y), tg1 = u8q(L[4].y), tl1 = u8q(L[5].y);
        const unsigned Gn = packG(gray1(pr0, pg0, pl0), gray1(tr0, tg0, tl0),
                                  gray1(pr1, pg1, pl1), gray1(tr1, tg1, tl1));
        const int Pkna = (int)(fabsf(pr0 - tr0) + fabsf(pg0 - tg0) + fabsf(pl0 - tl0))
                       | ((int)((pr0 + pg0) + pl0) << 10)
                       | ((int)((tr0 + tg0) + tl0) << 20);
        const int Pknb = (int)(fabsf(pr1 - tr1) + fabsf(pg1 - tg1) + fabsf(pl1 - tl1))
                       | ((int)((pr1 + pg1) + pl1) << 10)
                       | ((int)((tr1 + tg1) + tl1) << 20);
        // ---- boundary gray (lanes 0/63) ----
        unsigned Gxn = 0;
        if (isb) {
            Gxn = packG(gray1(u8q(bv[0]), u8q(bv[1]), u8q(bv[2])),
                        gray1(u8q(bv[3]), u8q(bv[4]), u8q(bv[5])),
                        gray1(u8q(bv[6]), u8q(bv[7]), u8q(bv[8])),
                        gray1(u8q(bv[9]), u8q(bv[10]), u8q(bv[11])));
        }
        unsigned mkn = 0;
        if (i >= 2) {
            // ---- sobel row s = gy-1 (rows G1, G2, Gn) ----
            const unsigned GL = (unsigned)__shfl_up((int)G2, 1, 64);
            const unsigned GR = (unsigned)__shfl_down((int)G2, 1, 64);
            const unsigned lv = (lane == 0) ? Gx2 : GL;    // col x0-1 in bytes 2,3
            const unsigned rv = (lane == 63) ? Gx2 : GR;   // col x0+2 in bytes 0,1
            const int sp0 = sob1((int)((lv >> 16) & 255), (int)((G2 >> 16) & 255),
                                 (int)(G1 & 255), (int)(Gn & 255));
            const int st0 = sob1((int)((lv >> 24) & 255), (int)((G2 >> 24) & 255),
                                 (int)((G1 >> 8) & 255), (int)((Gn >> 8) & 255));
            const int sp1 = sob1((int)(G2 & 255), (int)(rv & 255),
                                 (int)((G1 >> 16) & 255), (int)((Gn >> 16) & 255));
            const int st1 = sob1((int)((G2 >> 8) & 255), (int)((rv >> 8) & 255),
                                 (int)((G1 >> 24) & 255), (int)((Gn >> 24) & 255));
            // boundary col (lane0: x0-1, lane63: x0+2); garbage on other lanes (unread)
            const bool s0l = (lane == 0);
            const int xl_p = s0l ? (int)(Gx2 & 255)        : (int)((G2 >> 16) & 255);
            const int xl_t = s0l ? (int)((Gx2 >> 8) & 255) : (int)((G2 >> 24) & 255);
            const int xr_p = s0l ? (int)(G2 & 255)         : (int)((Gx2 >> 16) & 255);
            const int xr_t = s0l ? (int)((G2 >> 8) & 255)  : (int)((Gx2 >> 24) & 255);
            const int xu_p = s0l ? (int)((Gx1 >> 16) & 255) : (int)(Gx1 & 255);
            const int xu_t = s0l ? (int)((Gx1 >> 24) & 255) : (int)((Gx1 >> 8) & 255);
            const int xd_p = s0l ? (int)((Gxn >> 16) & 255) : (int)(Gxn & 255);
            const int xd_t = s0l ? (int)((Gxn >> 24) & 255) : (int)((Gxn >> 8) & 255);
            const int spx = sob1(xl_p, xr_p, xu_p, xd_p);
            const int stx = sob1(xl_t, xr_t, xu_t, xd_t);
            mkn = (unsigned)((sp0 > 10 ? 1 : 0) | (st0 > 10 ? 2 : 0)
                  | ((sp1 > 10 ? 1 : 0) | (st1 > 10 ? 2 : 0)) << 2
                  | ((spx > 10 ? 1 : 0) | (stx > 10 ? 2 : 0)) << 4);
            if (i >= 3 && i <= 18) accS += iabs(sp0 - st0) + iabs(sp1 - st1);
            if (i >= 4) {
                // ---- output row o = gy-2: blur>0 == OR over 3x3 codes ----
                const unsigned VO = mk1 | mk2 | mkn;
                const unsigned VOL = (unsigned)__shfl_up((int)VO, 1, 64);
                const unsigned VOR = (unsigned)__shfl_down((int)VO, 1, 64);
                const unsigned vl = (lane == 0) ? (VO >> 4) : (VOL >> 2);
                const unsigned vr = (lane == 63) ? (VO >> 4) : VOR;
                const unsigned k0 = (VO | vl | (VO >> 2)) & 3u;
                const unsigned k1 = ((VO >> 2) | VO | vr) & 3u;
                {
                    const int D = Pk1a & 1023, Su = (Pk1a >> 10) & 1023, St = Pk1a >> 20;
                    accE += (k0 & 1u) ? ((k0 & 2u) ? D : Su) : ((k0 & 2u) ? St : 0);
                }
                {
                    const int D = Pk1b & 1023, Su = (Pk1b >> 10) & 1023, St = Pk1b >> 20;
                    accE += (k1 & 1u) ? ((k1 & 2u) ? D : Su) : ((k1 & 2u) ? St : 0);
                }
            }
        }
        // ---- rotate pipeline ----
        G1 = G2; G2 = Gn;
        Gx1 = Gx2; Gx2 = Gxn;
        mk1 = mk2; mk2 = mkn;
        Pk1a = Pk2a; Pk1b = Pk2b; Pk2a = Pkna; Pk2b = Pknb;
        // ---- prefetch ----
        if (i < 18) ldMain(gy + 2, L);
        if (i < 19) ldBound(gy + 1);
    };

    for (int i = 0; i < 2 + BH + 2; i += 2) {   // 20 iterations
        step(i, LA);
        step(i + 1, LB);
    }

    // ---- wave reduce -> per-block int2 ----
    #pragma unroll
    for (int off = 32; off > 0; off >>= 1) {
        accS += __shfl_down(accS, off, 64);
        accE += __shfl_down(accE, off, 64);
    }
    __shared__ int wss[4], wse[4];
    const int wv = tid >> 6;
    if (lane == 0) { wss[wv] = accS; wse[wv] = accE; }
    __syncthreads();
    if (tid == 0) {
        ws[blockIdx.x] = make_int2((wss[0] + wss[1]) + (wss[2] + wss[3]),
                                   (wse[0] + wse[1]) + (wse[2] + wse[3]));
    }
}

__global__ __launch_bounds__(256)
void reduce_kernel(const int2* __restrict__ ws, float* __restrict__ out) {
    const int tid = threadIdx.x;
    int s = 0, e = 0;
    for (int i = tid; i < NBLK; i += 256) {
        const int2 v = ws[i];
        s += v.x; e += v.y;
    }
    double ds = (double)s, de = (double)e;
    #pragma unroll
    for (int off = 32; off > 0; off >>= 1) {
        ds += __shfl_down(ds, off, 64);
        de += __shfl_down(de, off, 64);
    }
    __shared__ double rs[4], re[4];
    const int wave = tid >> 6, lane = tid & 63;
    if (lane == 0) { rs[wave] = ds; re[wave] = de; }
    __syncthreads();
    if (tid == 0) {
        const double ts = (rs[0] + rs[1]) + (rs[2] + rs[3]);
        const double te = (re[0] + re[1]) + (re[2] + re[3]);
        const float inv_s = 1.0f / (255.0f * (float)Bn * (float)Hn * (float)Wn);
        out[0] = (float)ts * inv_s;
        out[1] = (float)te * (inv_s / 3.0f);
    }
}

extern "C" void kernel_launch(void* const* d_in, const int* in_sizes, int n_in,
                              void* d_out, int out_size, void* d_ws, size_t ws_size,
                              hipStream_t stream) {
    const float* pred = (const float*)d_in[0];
    const float* tru  = (const float*)d_in[1];
    float* out = (float*)d_out;
    int2* ws = (int2*)d_ws;   // NBLK int2 partials = 4 KB

    csl_stream<<<NBLK, 256, 0, stream>>>(pred, tru, ws);
    reduce_kernel<<<1, 256, 0, stream>>>(ws, out);
}